// Round 1
// baseline (989.772 us; speedup 1.0000x reference)
//
#include <hip/hip_runtime.h>

// Attractor: hs <- normalize(leaky_relu(0.5*hs + h@M)), TAU=16, B=8, D=8192 (fp32 I/O).
//
// R4: MFMA rewrite. R3 post-mortem: 956 us spread over 35 dispatches; matmul ran
// at ~2.9 TB/s on an L3-resident 128 MiB stream, VALU-bound (17.2 GFLOP on the
// 103 TF vector pipe >= 167 us floor) plus 512 MiB of partial traffic + 16 reduce
// launches. R4 moves the matmul to the matrix pipe and fuses everything:
//   - pack_M: M fp32 -> bf16 B-fragments [nt][kt][lane][8] (128 MiB). Step-kernel
//     B loads become contiguous 1 KiB/wave ushort8 -> full L3 streaming rate.
//   - hi/lo trick: A operand rows 0-7 = bf16(h), rows 8-15 = bf16(h - hi). One
//     mfma_f32_16x16x32_bf16 computes both; epilogue sums D[r]+D[r+8] -> h keeps
//     ~16 mantissa bits (fp32-ish), M stays bf16 (same as passing R3).
//   - step_kernel x16: 256 blocks x 512 thr, block owns 32 cols x full K (no
//     partials). 8 waves split K, LDS-reduce, epilogue applies inv_prev/decay/
//     leaky (deferred-inv algebra), 8 ss-atomics/block, and packs its 32 cols
//     (= exactly one A k-tile) into the next step's A-fragment buffer.
// A-pack and B-pack use the same lane->k bijection (k = 8*(lane>>4)+j), so the
// MFMA k-pairing is consistent by construction; D layout col=lane&15,
// row=(lane>>4)*4+reg (m89-verified).

#define DD 8192
#define BB 8
#define TAU 16
#define NT 512      // n-tiles (16 cols each)
#define KT 256      // k-tiles (32 k each)
#define DECAYF 0.5f
#define SLOPEF 0.01f
#define EPSF 1e-12f

typedef __attribute__((ext_vector_type(8))) short short8v;
typedef __attribute__((ext_vector_type(8))) unsigned short ushort8v;
typedef __attribute__((ext_vector_type(4))) float float4v;

static __device__ __forceinline__ float b2f(unsigned short u) {
    union { unsigned int i; float f; } v; v.i = ((unsigned int)u) << 16; return v.f;
}
static __device__ __forceinline__ unsigned short f2b(float f) {
    union { float f; unsigned int i; } v; v.f = f;
    unsigned int r = v.i + 0x7FFFu + ((v.i >> 16) & 1u);   // RNE
    return (unsigned short)(r >> 16);
}

// M fp32 (k-major rows, n contiguous) -> Bpack bf16 fragments.
// Fragment slot (lane l, elem j) of tile (nt,kt) = M[kt*32 + 8*(l>>4) + j][nt*16 + (l&15)].
// One wave per tile; 4 waves/block cover 4 consecutive nt (same kt) so the
// 16-lane 64 B read chunks tile into full 256 B rows. NT loads keep M's one-shot
// 256 MiB stream from evicting freshly written Bpack out of L3.
__global__ __launch_bounds__(256) void pack_M_kernel(const float* __restrict__ M,
                                                     unsigned short* __restrict__ Bp) {
    const int w = threadIdx.x >> 6, l = threadIdx.x & 63;
    const unsigned int wid = blockIdx.x * 4 + w;   // 0..131071
    const int kt = wid >> 9;                       // 0..255
    const int nt = wid & 511;                      // 0..511
    const int col = nt * 16 + (l & 15);
    const int k0  = kt * 32 + (l >> 4) * 8;
    const float* src = M + (size_t)k0 * DD + col;
    ushort8v o;
#pragma unroll
    for (int j = 0; j < 8; j++) o[j] = f2b(__builtin_nontemporal_load(src + (size_t)j * DD));
    *(ushort8v*)(Bp + ((size_t)nt * KT + kt) * 512 + (size_t)l * 8) = o;
}

// x fp32 (8 x 8192) -> A fragments for step 0. Rows 0-7 hi, 8-15 lo.
__global__ __launch_bounds__(256) void pack_x_kernel(const float* __restrict__ x,
                                                     unsigned short* __restrict__ Ap) {
    const int w = threadIdx.x >> 6, l = threadIdx.x & 63;
    const int kt = blockIdx.x * 4 + w;             // 0..255
    const int row = l & 15;
    const int k0  = kt * 32 + (l >> 4) * 8;
    const float* src = x + (size_t)(row & 7) * DD + k0;
    ushort8v o;
#pragma unroll
    for (int j = 0; j < 8; j++) {
        const float v = src[j];
        const unsigned short h = f2b(v);
        o[j] = (row < 8) ? h : f2b(v - b2f(h));
    }
    *(ushort8v*)(Ap + (size_t)kt * 512 + (size_t)l * 8) = o;
}

// One full recurrence step. 256 blocks x 512 threads (8 waves).
// Block owns cols [bid*32, bid*32+32) = n-tiles {2*bid, 2*bid+1}, full K.
// Wave w handles k-tiles [w*32, w*32+32).
__global__ __launch_bounds__(512) void step_kernel(const unsigned short* __restrict__ Ap_cur,
                                                   const unsigned short* __restrict__ Bp,
                                                   const float* __restrict__ act_prev,
                                                   const float* __restrict__ ss_prev,
                                                   float* __restrict__ act_new,
                                                   unsigned short* __restrict__ Ap_next,
                                                   float* __restrict__ ss_new) {
    const int tid = threadIdx.x;
    const int w = tid >> 6, l = tid & 63;
    const int bid = blockIdx.x;
    const int col0 = bid * 32;

    float4v acc0 = {0.f, 0.f, 0.f, 0.f}, acc1 = {0.f, 0.f, 0.f, 0.f};
    const unsigned short* Abase = Ap_cur + (size_t)l * 8;
    const unsigned short* B0 = Bp + ((size_t)(2 * bid)     * KT) * 512 + (size_t)l * 8;
    const unsigned short* B1 = Bp + ((size_t)(2 * bid + 1) * KT) * 512 + (size_t)l * 8;
    const int ktbase = w * 32;
#pragma unroll 4
    for (int i = 0; i < 32; i++) {
        const size_t off = (size_t)(ktbase + i) * 512;
        const short8v a  = *(const short8v*)(Abase + off);
        const short8v b0 = *(const short8v*)(B0 + off);
        const short8v b1 = *(const short8v*)(B1 + off);
        acc0 = __builtin_amdgcn_mfma_f32_16x16x32_bf16(a, b0, acc0, 0, 0, 0);
        acc1 = __builtin_amdgcn_mfma_f32_16x16x32_bf16(a, b1, acc1, 0, 0, 0);
    }

    // De-fragment + cross-wave K reduction in LDS.
    // D layout: col = lane&15, row = (lane>>4)*4 + reg (m89).
    __shared__ float red[8][16][33];
    {
        const int rbase = (l >> 4) * 4, c = l & 15;
#pragma unroll
        for (int q = 0; q < 4; q++) {
            red[w][rbase + q][c]      = acc0[q];
            red[w][rbase + q][16 + c] = acc1[q];
        }
    }
    __syncthreads();

    if (tid < 256) {
        const int r = tid >> 5, c = tid & 31;
        float s = 0.f;
#pragma unroll
        for (int u = 0; u < 8; u++) s += red[u][r][c] + red[u][r + 8][c];  // hi + lo
        float v;
        if (ss_prev) {
            const float inv = 1.0f / fmaxf(sqrtf(ss_prev[r]), EPSF);
            v = inv * (s + DECAYF * act_prev[(size_t)r * DD + col0 + c]);
        } else {
            v = s;   // step 0: hs_prev = 0, h = x
        }
        const float a = (v >= 0.f) ? v : SLOPEF * v;
        act_new[(size_t)r * DD + col0 + c] = a;

        float t2 = a * a;
#pragma unroll
        for (int off = 16; off > 0; off >>= 1) t2 += __shfl_down(t2, off, 32);
        if ((tid & 31) == 0) atomicAdd(&ss_new[r], t2);

        red[0][r][c] = a;   // each thread overwrites exactly the slot it read
    }
    __syncthreads();

    // Pack this block's 32 cols = A k-tile (kt_next == bid) for the next step.
    if (w == 0) {
        const int row = l & 15;
        const int kb  = (l >> 4) * 8;
        ushort8v o;
#pragma unroll
        for (int j = 0; j < 8; j++) {
            const float v = red[0][row & 7][kb + j];
            const unsigned short h = f2b(v);
            o[j] = (row < 8) ? h : f2b(v - b2f(h));
        }
        *(ushort8v*)(Ap_next + (size_t)bid * 512 + (size_t)l * 8) = o;
    }
}

// out = act * inv(row_ss). grid 64 x 1024.
__global__ __launch_bounds__(1024) void scale_kernel(const float* __restrict__ act,
                                                     const float* __restrict__ ss,
                                                     float* __restrict__ out) {
    const int e = blockIdx.x * 1024 + threadIdx.x;
    const float inv = 1.0f / fmaxf(sqrtf(ss[e >> 13]), EPSF);
    out[e] = act[e] * inv;
}

extern "C" void kernel_launch(void* const* d_in, const int* in_sizes, int n_in,
                              void* d_out, int out_size, void* d_ws, size_t ws_size,
                              hipStream_t stream) {
    const float* x = (const float*)d_in[0];   // (8, 8192)
    const float* M = (const float*)d_in[1];   // (8192, 8192)

    const size_t szB = (size_t)NT * KT * 1024;             // Bpack: 128 MiB
    const size_t szA = (size_t)KT * 1024;                  // Apack: 256 KiB
    const size_t szF = (size_t)BB * DD * sizeof(float);    // act:   256 KiB
    const size_t szS = (size_t)TAU * BB * sizeof(float);   // ss:    512 B

    char* p = (char*)d_ws;
    unsigned short* Bp  = (unsigned short*)p; p += szB;
    unsigned short* Ap0 = (unsigned short*)p; p += szA;
    unsigned short* Ap1 = (unsigned short*)p; p += szA;
    float* act0 = (float*)p; p += szF;
    float* act1 = (float*)p; p += szF;
    float* row_ss = (float*)p;

    hipMemsetAsync(row_ss, 0, szS, stream);
    pack_x_kernel<<<64, 256, 0, stream>>>(x, Ap0);
    pack_M_kernel<<<32768, 256, 0, stream>>>(M, Bp);

    unsigned short* Aps[2] = {Ap0, Ap1};
    float* acts[2] = {act0, act1};
    for (int t = 0; t < TAU; t++) {
        step_kernel<<<256, 512, 0, stream>>>(
            Aps[t & 1], Bp,
            acts[(t + 1) & 1],
            t ? (row_ss + (t - 1) * BB) : (const float*)nullptr,
            acts[t & 1],
            Aps[(t + 1) & 1],
            row_ss + t * BB);
    }
    scale_kernel<<<64, 1024, 0, stream>>>(acts[1], row_ss + (TAU - 1) * BB, (float*)d_out);
}

// Round 2
// 815.661 us; speedup vs baseline: 1.2135x; 1.2135x over previous
//
#include <hip/hip_runtime.h>

// Attractor: hs <- normalize(leaky_relu(0.5*hs + h@M)), TAU=16, B=8, D=8192 (fp32 I/O).
//
// R5: concurrency fix. R4 post-mortem: 990 us ~= R3's 956 despite moving matmul
// from VALU to MFMA. Steps ran ~56 us = 2.2 TB/s on an L3-resident 128 MiB
// stream; R3's matmul also ~2.5 TB/s. Common factor: both at 2048 waves =
// 8 waves/CU. MFMA math is ~0.3 us/step (pipe ~1% busy) -> the step kernel is a
// latency-bound load loop at 1/4 the concurrency needed (~10 B/cyc/CU in flight
// vs ~600-900 cyc L3 latency). R5:
//   - 512 blocks x 8 waves (1 n-tile/block, full K) = 16 waves/CU, 2 blocks/CU
//     (__launch_bounds__(512,4) caps VGPR at 128).
//   - inner loop batches 8 k-tiles: 16x16B loads in flight before first MFMA wait.
//   - ss atomics spread over 8 slots/row (64/address instead of 512); consumers
//     sum 8 slots. A-pack: block pair each writes half its A k-tile.
// Layouts unchanged from R4: Bpack [nt][kt][lane][8] bf16, A hi/lo trick (rows
// 0-7 = bf16(h), 8-15 = bf16(h-hi), epilogue sums D[r]+D[r+8]), D mapping
// col=lane&15, row=(lane>>4)*4+reg (m89-verified).

#define DD 8192
#define BB 8
#define TAU 16
#define NT 512      // n-tiles (16 cols each)
#define KT 256      // k-tiles (32 k each)
#define DECAYF 0.5f
#define SLOPEF 0.01f
#define EPSF 1e-12f

typedef __attribute__((ext_vector_type(8))) short short8v;
typedef __attribute__((ext_vector_type(8))) unsigned short ushort8v;
typedef __attribute__((ext_vector_type(4))) float float4v;

static __device__ __forceinline__ float b2f(unsigned short u) {
    union { unsigned int i; float f; } v; v.i = ((unsigned int)u) << 16; return v.f;
}
static __device__ __forceinline__ unsigned short f2b(float f) {
    union { float f; unsigned int i; } v; v.f = f;
    unsigned int r = v.i + 0x7FFFu + ((v.i >> 16) & 1u);   // RNE
    return (unsigned short)(r >> 16);
}

// M fp32 (k-major rows, n contiguous) -> Bpack bf16 fragments.
// Fragment slot (lane l, elem j) of tile (nt,kt) = M[kt*32 + 8*(l>>4) + j][nt*16 + (l&15)].
__global__ __launch_bounds__(256) void pack_M_kernel(const float* __restrict__ M,
                                                     unsigned short* __restrict__ Bp) {
    const int w = threadIdx.x >> 6, l = threadIdx.x & 63;
    const unsigned int wid = blockIdx.x * 4 + w;   // 0..131071
    const int kt = wid >> 9;                       // 0..255
    const int nt = wid & 511;                      // 0..511
    const int col = nt * 16 + (l & 15);
    const int k0  = kt * 32 + (l >> 4) * 8;
    const float* src = M + (size_t)k0 * DD + col;
    ushort8v o;
#pragma unroll
    for (int j = 0; j < 8; j++) o[j] = f2b(__builtin_nontemporal_load(src + (size_t)j * DD));
    *(ushort8v*)(Bp + ((size_t)nt * KT + kt) * 512 + (size_t)l * 8) = o;
}

// x fp32 (8 x 8192) -> A fragments for step 0. Rows 0-7 hi, 8-15 lo.
__global__ __launch_bounds__(256) void pack_x_kernel(const float* __restrict__ x,
                                                     unsigned short* __restrict__ Ap) {
    const int w = threadIdx.x >> 6, l = threadIdx.x & 63;
    const int kt = blockIdx.x * 4 + w;             // 0..255
    const int row = l & 15;
    const int k0  = kt * 32 + (l >> 4) * 8;
    const float* src = x + (size_t)(row & 7) * DD + k0;
    ushort8v o;
#pragma unroll
    for (int j = 0; j < 8; j++) {
        const float v = src[j];
        const unsigned short h = f2b(v);
        o[j] = (row < 8) ? h : f2b(v - b2f(h));
    }
    *(ushort8v*)(Ap + (size_t)kt * 512 + (size_t)l * 8) = o;
}

// One full recurrence step. 512 blocks x 512 threads (8 waves), 2 blocks/CU.
// Block owns n-tile bid (16 cols), full K. Wave w: k-tiles [w*32, w*32+32).
__global__ __launch_bounds__(512, 4) void step_kernel(const unsigned short* __restrict__ Ap_cur,
                                                      const unsigned short* __restrict__ Bp,
                                                      const float* __restrict__ act_prev,
                                                      const float* __restrict__ ss_prev,
                                                      float* __restrict__ act_new,
                                                      unsigned short* __restrict__ Ap_next,
                                                      float* __restrict__ ss_new) {
    const int tid = threadIdx.x;
    const int w = tid >> 6, l = tid & 63;
    const int bid = blockIdx.x;
    const int col0 = bid * 16;

    float4v acc = {0.f, 0.f, 0.f, 0.f};
    const unsigned short* Ab = Ap_cur + (size_t)(w * 32) * 512 + (size_t)l * 8;
    const unsigned short* Bb = Bp + ((size_t)bid * KT + w * 32) * 512 + (size_t)l * 8;

#pragma unroll
    for (int i = 0; i < 32; i += 8) {
        short8v av[8], bv[8];
#pragma unroll
        for (int u = 0; u < 8; u++) {
            av[u] = *(const short8v*)(Ab + (size_t)(i + u) * 512);
            bv[u] = *(const short8v*)(Bb + (size_t)(i + u) * 512);
        }
#pragma unroll
        for (int u = 0; u < 8; u++)
            acc = __builtin_amdgcn_mfma_f32_16x16x32_bf16(av[u], bv[u], acc, 0, 0, 0);
    }

    // De-fragment + cross-wave K reduction in LDS.
    // D layout: col = lane&15, row = (lane>>4)*4 + reg (m89).
    __shared__ float red[8][16][17];
    {
        const int rbase = (l >> 4) * 4, c = l & 15;
#pragma unroll
        for (int q = 0; q < 4; q++) red[w][rbase + q][c] = acc[q];
    }
    __syncthreads();

    if (tid < 128) {
        const int r = tid >> 4, c = tid & 15;
        float s = 0.f;
#pragma unroll
        for (int u = 0; u < 8; u++) s += red[u][r][c] + red[u][r + 8][c];  // hi + lo
        float v;
        if (ss_prev) {
            float ss = 0.f;
#pragma unroll
            for (int u = 0; u < 8; u++) ss += ss_prev[r * 8 + u];
            const float inv = 1.0f / fmaxf(sqrtf(ss), EPSF);
            v = inv * (s + DECAYF * act_prev[(size_t)r * DD + col0 + c]);
        } else {
            v = s;   // step 0: hs_prev = 0, h = x
        }
        const float a = (v >= 0.f) ? v : SLOPEF * v;
        act_new[(size_t)r * DD + col0 + c] = a;

        float t2 = a * a;
#pragma unroll
        for (int off = 8; off > 0; off >>= 1) t2 += __shfl_down(t2, off, 16);
        if ((tid & 15) == 0) atomicAdd(&ss_new[r * 8 + (bid & 7)], t2);

        red[0][r][c] = a;   // stage act for the A-pack phase
    }
    __syncthreads();

    // Pack this block's 16 cols = half of A k-tile (bid>>1) for the next step.
    // Lanes with (l>>5) == (bid&1) own k-offsets {0..15} / {16..31} of the tile.
    if (w == 0 && (l >> 5) == (bid & 1)) {
        const int row = l & 15;
        const int kb  = 8 * (l >> 4) - 16 * (bid & 1);   // 0 or 8
        ushort8v o;
#pragma unroll
        for (int j = 0; j < 8; j++) {
            const float v = red[0][row & 7][kb + j];
            const unsigned short h = f2b(v);
            o[j] = (row < 8) ? h : f2b(v - b2f(h));
        }
        *(ushort8v*)(Ap_next + (size_t)(bid >> 1) * 512 + (size_t)l * 8) = o;
    }
}

// out = act * inv(sum of 8 ss slots per row). grid 64 x 1024.
__global__ __launch_bounds__(1024) void scale_kernel(const float* __restrict__ act,
                                                     const float* __restrict__ ss,
                                                     float* __restrict__ out) {
    const int e = blockIdx.x * 1024 + threadIdx.x;
    const int r = e >> 13;
    float s = 0.f;
#pragma unroll
    for (int u = 0; u < 8; u++) s += ss[r * 8 + u];
    const float inv = 1.0f / fmaxf(sqrtf(s), EPSF);
    out[e] = act[e] * inv;
}

extern "C" void kernel_launch(void* const* d_in, const int* in_sizes, int n_in,
                              void* d_out, int out_size, void* d_ws, size_t ws_size,
                              hipStream_t stream) {
    const float* x = (const float*)d_in[0];   // (8, 8192)
    const float* M = (const float*)d_in[1];   // (8192, 8192)

    const size_t szB = (size_t)NT * KT * 1024;             // Bpack: 128 MiB
    const size_t szA = (size_t)KT * 1024;                  // Apack: 256 KiB
    const size_t szF = (size_t)BB * DD * sizeof(float);    // act:   256 KiB
    const size_t szS = (size_t)TAU * BB * 8 * sizeof(float); // ss: 4 KiB (8 slots/row)

    char* p = (char*)d_ws;
    unsigned short* Bp  = (unsigned short*)p; p += szB;
    unsigned short* Ap0 = (unsigned short*)p; p += szA;
    unsigned short* Ap1 = (unsigned short*)p; p += szA;
    float* act0 = (float*)p; p += szF;
    float* act1 = (float*)p; p += szF;
    float* row_ss = (float*)p;

    hipMemsetAsync(row_ss, 0, szS, stream);
    pack_x_kernel<<<64, 256, 0, stream>>>(x, Ap0);
    pack_M_kernel<<<32768, 256, 0, stream>>>(M, Bp);

    unsigned short* Aps[2] = {Ap0, Ap1};
    float* acts[2] = {act0, act1};
    for (int t = 0; t < TAU; t++) {
        step_kernel<<<512, 512, 0, stream>>>(
            Aps[t & 1], Bp,
            acts[(t + 1) & 1],
            t ? (row_ss + (t - 1) * BB * 8) : (const float*)nullptr,
            acts[t & 1],
            Aps[(t + 1) & 1],
            row_ss + t * BB * 8);
    }
    scale_kernel<<<64, 1024, 0, stream>>>(acts[1], row_ss + (TAU - 1) * BB * 8, (float*)d_out);
}